// Round 1
// baseline (609.705 us; speedup 1.0000x reference)
//
#include <hip/hip_runtime.h>
#include <math.h>

typedef float v4 __attribute__((ext_vector_type(4)));

#define HD 1024      // hidden dim
#define NB 64        // batch
#define NCHUNK 16    // i-chunks in update kernel

// ws layout (float offsets)
#define WS_XT      0         // Xt4 [256][64] float4  = 65536 floats
#define WS_HT      65536     // Ht4 same
#define WS_IGT     131072    // igT [1024][64]
#define WS_FGT     196608    // fgT [1024][64]
#define WS_QT      262144    // qT  [1024][64]
#define WS_VT      327680    // vT  [1024][64]
#define WS_OGN     393216    // ogN [64][1024]
#define WS_KN      458752    // kN  [64][1024]
#define WS_PART    524288    // partial [16][64][1024] = 1048576 floats
// total = 1572864 floats = 6.29 MB

// ---------------- kernel 1: transpose input/h to k-major float4 panels ----------
__global__ __launch_bounds__(256) void k_transpose(const float* __restrict__ input,
                                                   const float* __restrict__ h,
                                                   float* __restrict__ ws) {
    int g = blockIdx.x * 256 + threadIdx.x;   // 0..32767
    int which = g >> 14;                      // 0=input, 1=h
    int idx = g & 16383;                      // 0..16383
    int kk = idx >> 6;                        // 0..255 (float4 index along k)
    int b  = idx & 63;
    const float* src = which ? h : input;
    v4 val = *(const v4*)(src + (size_t)b * HD + kk * 4);
    v4* dst = (v4*)(ws + (which ? WS_HT : WS_XT));
    dst[kk * 64 + b] = val;                   // coalesced: lanes consecutive in b
}

// ---------------- kernel 2: gates + q/k/v GEMM, 4 rows per wave ----------------
// Block = 128 threads (2 waves). Each wave computes 4 output rows over all 64
// batches (lanes = batch). Weight rows are wave-uniform streams; the x-panel
// float4 is loaded ONCE per k-step and reused by 4 accumulators -> 4x less L2
// activation traffic than the 1-row/wave version.
// grid: blocks 0..383 = gates (8 rows/block), 384..767 = q/k/v (8 rows/block).
__global__ __launch_bounds__(128) void k_gemm(
    const float* __restrict__ Wih, const float* __restrict__ Whh, const float* __restrict__ bias,
    const float* __restrict__ Wq, const float* __restrict__ Wqb,
    const float* __restrict__ Wk, const float* __restrict__ Wkb,
    const float* __restrict__ Wv, const float* __restrict__ Wvb,
    float* __restrict__ ws) {
    const v4* Xt = (const v4*)(ws + WS_XT);
    const v4* Ht = (const v4*)(ws + WS_HT);
    int lane = threadIdx.x & 63;
    int wid  = __builtin_amdgcn_readfirstlane(threadIdx.x >> 6);   // 0..1
    int blk  = blockIdx.x;

    if (blk < 384) {
        // gates rows r0..r0+3, r0 in [0,3072), multiple of 4 (never crosses a
        // 1024-row gate segment boundary)
        int r0 = blk * 8 + wid * 4;
        const v4* w1 = (const v4*)(Wih + (size_t)r0 * HD);
        const v4* w2 = (const v4*)(Whh + (size_t)r0 * HD);
        float a0 = 0.f, a1 = 0.f, a2 = 0.f, a3 = 0.f;
        #pragma unroll 4
        for (int kk = 0; kk < 256; ++kk) {
            v4 x  = Xt[kk * 64 + lane];
            v4 p0 = w1[kk];
            v4 p1 = w1[kk + 256];
            v4 p2 = w1[kk + 512];
            v4 p3 = w1[kk + 768];
            a0 += p0.x * x.x + p0.y * x.y + p0.z * x.z + p0.w * x.w;
            a1 += p1.x * x.x + p1.y * x.y + p1.z * x.z + p1.w * x.w;
            a2 += p2.x * x.x + p2.y * x.y + p2.z * x.z + p2.w * x.w;
            a3 += p3.x * x.x + p3.y * x.y + p3.z * x.z + p3.w * x.w;
        }
        #pragma unroll 4
        for (int kk = 0; kk < 256; ++kk) {
            v4 x  = Ht[kk * 64 + lane];
            v4 p0 = w2[kk];
            v4 p1 = w2[kk + 256];
            v4 p2 = w2[kk + 512];
            v4 p3 = w2[kk + 768];
            a0 += p0.x * x.x + p0.y * x.y + p0.z * x.z + p0.w * x.w;
            a1 += p1.x * x.x + p1.y * x.y + p1.z * x.z + p1.w * x.w;
            a2 += p2.x * x.x + p2.y * x.y + p2.z * x.z + p2.w * x.w;
            a3 += p3.x * x.x + p3.y * x.y + p3.z * x.z + p3.w * x.w;
        }
        a0 += bias[r0 + 0];
        a1 += bias[r0 + 1];
        a2 += bias[r0 + 2];
        a3 += bias[r0 + 3];
        int seg = r0 >> 10;                // 0=i, 1=f, 2=o (uniform for all 4 rows)
        if (seg == 0) {
            ws[WS_IGT + (r0 + 0) * 64 + lane] = expf(a0);
            ws[WS_IGT + (r0 + 1) * 64 + lane] = expf(a1);
            ws[WS_IGT + (r0 + 2) * 64 + lane] = expf(a2);
            ws[WS_IGT + (r0 + 3) * 64 + lane] = expf(a3);
        } else if (seg == 1) {
            int rr = r0 - 1024;
            ws[WS_FGT + (rr + 0) * 64 + lane] = expf(a0);
            ws[WS_FGT + (rr + 1) * 64 + lane] = expf(a1);
            ws[WS_FGT + (rr + 2) * 64 + lane] = expf(a2);
            ws[WS_FGT + (rr + 3) * 64 + lane] = expf(a3);
        } else {
            int rr = r0 - 2048;
            v4 o;
            o.x = 1.f / (1.f + expf(-a0));
            o.y = 1.f / (1.f + expf(-a1));
            o.z = 1.f / (1.f + expf(-a2));
            o.w = 1.f / (1.f + expf(-a3));
            *(v4*)(ws + WS_OGN + lane * HD + rr) = o;   // natural layout, v4
        }
    } else {
        // q/k/v rows r2..r2+3, r2 in [0,3072)
        int r2  = (blk - 384) * 8 + wid * 4;
        int sel = r2 >> 10;                 // uniform for all 4 rows
        int rr  = r2 & 1023;
        const float* W  = (sel == 0) ? Wq  : (sel == 1) ? Wk  : Wv;
        const float* Bv = (sel == 0) ? Wqb : (sel == 1) ? Wkb : Wvb;
        const v4* wr = (const v4*)(W + (size_t)rr * HD);
        float a0 = 0.f, a1 = 0.f, a2 = 0.f, a3 = 0.f;
        #pragma unroll 4
        for (int kk = 0; kk < 256; ++kk) {
            v4 x  = Xt[kk * 64 + lane];
            v4 p0 = wr[kk];
            v4 p1 = wr[kk + 256];
            v4 p2 = wr[kk + 512];
            v4 p3 = wr[kk + 768];
            a0 += p0.x * x.x + p0.y * x.y + p0.z * x.z + p0.w * x.w;
            a1 += p1.x * x.x + p1.y * x.y + p1.z * x.z + p1.w * x.w;
            a2 += p2.x * x.x + p2.y * x.y + p2.z * x.z + p2.w * x.w;
            a3 += p3.x * x.x + p3.y * x.y + p3.z * x.z + p3.w * x.w;
        }
        a0 += Bv[rr + 0];
        a1 += Bv[rr + 1];
        a2 += Bv[rr + 2];
        a3 += Bv[rr + 3];
        if (sel == 0) {
            ws[WS_QT + (rr + 0) * 64 + lane] = a0;
            ws[WS_QT + (rr + 1) * 64 + lane] = a1;
            ws[WS_QT + (rr + 2) * 64 + lane] = a2;
            ws[WS_QT + (rr + 3) * 64 + lane] = a3;
        } else if (sel == 1) {
            v4 kv; kv.x = a0; kv.y = a1; kv.z = a2; kv.w = a3;
            *(v4*)(ws + WS_KN + lane * HD + rr) = kv;   // natural layout, v4
        } else {
            ws[WS_VT + (rr + 0) * 64 + lane] = a0;
            ws[WS_VT + (rr + 1) * 64 + lane] = a1;
            ws[WS_VT + (rr + 2) * 64 + lane] = a2;
            ws[WS_VT + (rr + 3) * 64 + lane] = a3;
        }
    }
}

// ---------------- kernel 3: C update + fused readout partials ----------------
// grid = 64 b * 16 chunks; block 256 threads, thread owns 4 columns (float4).
// Rows batched 4-deep: 4 NT loads in flight before compute/store.
__global__ __launch_bounds__(256) void k_update(const float* __restrict__ C,
                                                float* __restrict__ out,
                                                float* __restrict__ ws) {
    int b  = blockIdx.x >> 4;
    int c  = blockIdx.x & 15;
    int i0 = c << 6;
    int tid = threadIdx.x;

    __shared__ float fg_s[64], iv_s[64], q_s[64];
    if (tid < 64) {
        int i = i0 + tid;
        fg_s[tid] = ws[WS_FGT + i * 64 + b];
        iv_s[tid] = ws[WS_IGT + i * 64 + b] * ws[WS_VT + i * 64 + b];
        q_s[tid]  = ws[WS_QT + i * 64 + b];
    }
    __syncthreads();

    v4 k4 = *(const v4*)(ws + WS_KN + b * HD + tid * 4);
    const v4* Cb = (const v4*)(C + (size_t)b * HD * HD) + tid;            // + i*256 per row
    v4*       On = (v4*)(out + NB * HD + (size_t)b * HD * HD) + tid;
    v4 acc0 = {0.f, 0.f, 0.f, 0.f};
    v4 acc1 = {0.f, 0.f, 0.f, 0.f};

    for (int ii = 0; ii < 64; ii += 4) {
        size_t r0 = (size_t)(i0 + ii) * 256;
        v4 c0 = __builtin_nontemporal_load(&Cb[r0]);
        v4 c1 = __builtin_nontemporal_load(&Cb[r0 + 256]);
        v4 c2 = __builtin_nontemporal_load(&Cb[r0 + 512]);
        v4 c3 = __builtin_nontemporal_load(&Cb[r0 + 768]);

        float f0 = fg_s[ii + 0], g0 = iv_s[ii + 0], q0 = q_s[ii + 0];
        float f1 = fg_s[ii + 1], g1 = iv_s[ii + 1], q1 = q_s[ii + 1];
        float f2 = fg_s[ii + 2], g2 = iv_s[ii + 2], q2 = q_s[ii + 2];
        float f3 = fg_s[ii + 3], g3 = iv_s[ii + 3], q3 = q_s[ii + 3];

        v4 n0, n1, n2, n3;
        n0.x = f0 * c0.x + g0 * k4.x; n0.y = f0 * c0.y + g0 * k4.y;
        n0.z = f0 * c0.z + g0 * k4.z; n0.w = f0 * c0.w + g0 * k4.w;
        n1.x = f1 * c1.x + g1 * k4.x; n1.y = f1 * c1.y + g1 * k4.y;
        n1.z = f1 * c1.z + g1 * k4.z; n1.w = f1 * c1.w + g1 * k4.w;
        n2.x = f2 * c2.x + g2 * k4.x; n2.y = f2 * c2.y + g2 * k4.y;
        n2.z = f2 * c2.z + g2 * k4.z; n2.w = f2 * c2.w + g2 * k4.w;
        n3.x = f3 * c3.x + g3 * k4.x; n3.y = f3 * c3.y + g3 * k4.y;
        n3.z = f3 * c3.z + g3 * k4.z; n3.w = f3 * c3.w + g3 * k4.w;

        __builtin_nontemporal_store(n0, &On[r0]);
        __builtin_nontemporal_store(n1, &On[r0 + 256]);
        __builtin_nontemporal_store(n2, &On[r0 + 512]);
        __builtin_nontemporal_store(n3, &On[r0 + 768]);

        acc0.x += q0 * n0.x; acc0.y += q0 * n0.y; acc0.z += q0 * n0.z; acc0.w += q0 * n0.w;
        acc1.x += q1 * n1.x; acc1.y += q1 * n1.y; acc1.z += q1 * n1.z; acc1.w += q1 * n1.w;
        acc0.x += q2 * n2.x; acc0.y += q2 * n2.y; acc0.z += q2 * n2.z; acc0.w += q2 * n2.w;
        acc1.x += q3 * n3.x; acc1.y += q3 * n3.y; acc1.z += q3 * n3.z; acc1.w += q3 * n3.w;
    }
    v4 acc;
    acc.x = acc0.x + acc1.x; acc.y = acc0.y + acc1.y;
    acc.z = acc0.z + acc1.z; acc.w = acc0.w + acc1.w;
    *(v4*)(ws + WS_PART + (size_t)(c * 64 + b) * HD + tid * 4) = acc;
}

// ---------------- kernel 4: finalize h ----------------
__global__ __launch_bounds__(256) void k_final(float* __restrict__ out,
                                               const float* __restrict__ ws) {
    int b = blockIdx.x;
    int tid = threadIdx.x;
    const v4* part = (const v4*)(ws + WS_PART);
    v4 s = {0.f, 0.f, 0.f, 0.f};
    for (int c = 0; c < NCHUNK; ++c) {
        v4 p = part[(size_t)(c * 64 + b) * 256 + tid];
        s.x += p.x; s.y += p.y; s.z += p.z; s.w += p.w;
    }
    v4 o4 = *(const v4*)(ws + WS_OGN + b * HD + tid * 4);
    v4 r;
    r.x = o4.x * s.x; r.y = o4.y * s.y; r.z = o4.z * s.z; r.w = o4.w * s.w;
    *(v4*)(out + b * HD + tid * 4) = r;
}

extern "C" void kernel_launch(void* const* d_in, const int* in_sizes, int n_in,
                              void* d_out, int out_size, void* d_ws, size_t ws_size,
                              hipStream_t stream) {
    const float* input = (const float*)d_in[0];
    const float* h     = (const float*)d_in[1];
    const float* C     = (const float*)d_in[2];
    const float* Wih   = (const float*)d_in[3];
    const float* Whh   = (const float*)d_in[4];
    const float* bias  = (const float*)d_in[5];
    const float* Wq_w  = (const float*)d_in[6];
    const float* Wq_b  = (const float*)d_in[7];
    const float* Wk_w  = (const float*)d_in[8];
    const float* Wk_b  = (const float*)d_in[9];
    const float* Wv_w  = (const float*)d_in[10];
    const float* Wv_b  = (const float*)d_in[11];
    float* out = (float*)d_out;
    float* ws  = (float*)d_ws;

    k_transpose<<<128, 256, 0, stream>>>(input, h, ws);
    k_gemm<<<768, 128, 0, stream>>>(Wih, Whh, bias, Wq_w, Wq_b, Wk_w, Wk_b, Wv_w, Wv_b, ws);
    k_update<<<1024, 256, 0, stream>>>(C, out, ws);
    k_final<<<64, 256, 0, stream>>>(out, ws);
}

// Round 2
// 503.438 us; speedup vs baseline: 1.2111x; 1.2111x over previous
//
#include <hip/hip_runtime.h>
#include <math.h>

typedef float v4 __attribute__((ext_vector_type(4)));
typedef float f32x4 __attribute__((ext_vector_type(4)));
typedef __bf16 bf16x8 __attribute__((ext_vector_type(8)));
typedef unsigned short u16;
typedef unsigned short u16x8 __attribute__((ext_vector_type(8)));

#define HD 1024      // hidden dim
#define NB 64        // batch
#define NCHUNK 16    // i-chunks in update kernel

// ws layout (float offsets)
#define WS_IGT     131072    // igT [1024][64]
#define WS_FGT     196608    // fgT [1024][64]
#define WS_QT      262144    // qT  [1024][64]
#define WS_VT      327680    // vT  [1024][64]
#define WS_OGN     393216    // ogN [64][1024]
#define WS_KN      458752    // kN  [64][1024]
#define WS_PART    524288    // partial [16][64][1024] = 1048576 floats
#define WS_BPK     1572864   // bf16 x/h fragments [64 ks][4 btile][64 lane][8] = 65536 f
#define WS_WPK     1638400   // bf16 weights, fragment order: 1,179,648 groups of 8 = 4,718,592 f
#define WPK_QGRP   786432    // group offset of qkv weights inside WPK (gates use 192*64*64 groups)
#define WS_PG      6356992   // gates partials [16 c][192 t][16 r][64 b] = 3,145,728 f
#define WS_PQ      9502720   // qkv  partials [ 8 c][192 t][16 r][64 b] = 1,572,864 f
// total = 11,075,584 floats = 44.3 MB

static __device__ __forceinline__ u16 f2bf(float f) {
    unsigned u = __float_as_uint(f);
    u += 0x7FFFu + ((u >> 16) & 1u);       // round-to-nearest-even
    return (u16)(u >> 16);
}

// ---------------- kernel 1: pack weights + activations to bf16 MFMA fragments ----
// Fragment layouts (mfma_f32_16x16x32_bf16):
//   A (weights): lane l holds W[t*16 + (l&15)][ks*32 + (l>>4)*8 + j], j=0..7
//   B (x/h):     lane l holds X[16*j_tile + (l&15)][ks*32 + (l>>4)*8 + j]
__global__ __launch_bounds__(256) void k_prep(
    const float* __restrict__ input, const float* __restrict__ h,
    const float* __restrict__ Wih, const float* __restrict__ Whh,
    const float* __restrict__ Wq, const float* __restrict__ Wk, const float* __restrict__ Wv,
    float* __restrict__ ws) {
    u16* wpk = (u16*)(ws + WS_WPK);
    u16* bpk = (u16*)(ws + WS_BPK);
    int g = blockIdx.x * 256 + threadIdx.x;

    if (g < 1179648) {
        // one 8-wide bf16 group per thread; source read = 32B coalesced
        const float* src;
        size_t dst;
        if (g < 393216) {                       // Wih -> gates ksteps 0..31
            int r = g >> 7, k8 = g & 127;
            src = Wih + (size_t)r * HD + k8 * 8;
            int t = r >> 4, ks = k8 >> 2;
            dst = ((size_t)(t * 64 + ks) * 64 + (((k8 & 3) << 4) | (r & 15))) * 8;
        } else if (g < 786432) {                // Whh -> gates ksteps 32..63
            int gi = g - 393216;
            int r = gi >> 7, k8 = gi & 127;
            src = Whh + (size_t)r * HD + k8 * 8;
            int t = r >> 4, ks = 32 + (k8 >> 2);
            dst = ((size_t)(t * 64 + ks) * 64 + (((k8 & 3) << 4) | (r & 15))) * 8;
        } else {                                // Wq/Wk/Wv -> qkv ksteps 0..31
            int gi = g - 786432;
            int r2 = gi >> 7, k8 = gi & 127;
            int sel = r2 >> 10, rr = r2 & 1023;
            const float* W = (sel == 0) ? Wq : (sel == 1) ? Wk : Wv;
            src = W + (size_t)rr * HD + k8 * 8;
            int t = r2 >> 4, ks = k8 >> 2;
            dst = (size_t)WPK_QGRP * 8 + ((size_t)(t * 32 + ks) * 64 + (((k8 & 3) << 4) | (r2 & 15))) * 8;
        }
        v4 f0 = *(const v4*)src;
        v4 f1 = *(const v4*)(src + 4);
        u16x8 pk;
        pk[0] = f2bf(f0.x); pk[1] = f2bf(f0.y); pk[2] = f2bf(f0.z); pk[3] = f2bf(f0.w);
        pk[4] = f2bf(f1.x); pk[5] = f2bf(f1.y); pk[6] = f2bf(f1.z); pk[7] = f2bf(f1.w);
        *(u16x8*)(wpk + dst) = pk;
    } else {
        // B fragments: x (ksteps 0..31) then h (32..63)
        int o = g - 1179648;                    // 0..16383
        int l = o & 63, jj = (o >> 6) & 3, ks2 = o >> 8;
        const float* srcm = (ks2 < 32) ? input : h;
        const float* src = srcm + (size_t)(jj * 16 + (l & 15)) * HD + (ks2 & 31) * 32 + (l >> 4) * 8;
        v4 f0 = *(const v4*)src;
        v4 f1 = *(const v4*)(src + 4);
        u16x8 pk;
        pk[0] = f2bf(f0.x); pk[1] = f2bf(f0.y); pk[2] = f2bf(f0.z); pk[3] = f2bf(f0.w);
        pk[4] = f2bf(f1.x); pk[5] = f2bf(f1.y); pk[6] = f2bf(f1.z); pk[7] = f2bf(f1.w);
        *(u16x8*)(bpk + (size_t)o * 8) = pk;
    }
}

// ---------------- kernel 2: MFMA GEMM, K-chunked with fp32 partials -------------
// One wave = one 16-row tile x 64 batch x K-chunk of 128 (4 ksteps of 32).
// gates: 192 tiles x 16 chunks = 3072 waves (K=2048: x then h)
// qkv:   192 tiles x  8 chunks = 1536 waves (K=1024)
__global__ __launch_bounds__(256) void k_mfma(float* __restrict__ ws) {
    int lane = threadIdx.x & 63;
    int w = blockIdx.x * 4 + (threadIdx.x >> 6);
    const bf16x8* Wp = (const bf16x8*)(ws + WS_WPK);
    const bf16x8* Bp = (const bf16x8*)(ws + WS_BPK);

    size_t aBase;
    int ks0;
    float* pout;
    if (w < 3072) {
        int t = w >> 4, c = w & 15;
        ks0 = c * 4;
        aBase = (size_t)(t * 64 + ks0) * 64;
        pout = ws + WS_PG + (size_t)(c * 192 + t) * 1024;
    } else {
        int w2 = w - 3072;
        int t = w2 >> 3, c = w2 & 7;
        ks0 = c * 4;
        aBase = (size_t)WPK_QGRP + (size_t)(t * 32 + ks0) * 64;
        pout = ws + WS_PQ + (size_t)(c * 192 + t) * 1024;
    }

    f32x4 a0 = {0.f, 0.f, 0.f, 0.f};
    f32x4 a1 = a0, a2 = a0, a3 = a0;
    #pragma unroll
    for (int s = 0; s < 4; ++s) {
        bf16x8 a = Wp[aBase + (size_t)s * 64 + lane];
        int kb = (ks0 + s) * 4;
        bf16x8 b0 = Bp[(size_t)(kb + 0) * 64 + lane];
        bf16x8 b1 = Bp[(size_t)(kb + 1) * 64 + lane];
        bf16x8 b2 = Bp[(size_t)(kb + 2) * 64 + lane];
        bf16x8 b3 = Bp[(size_t)(kb + 3) * 64 + lane];
        a0 = __builtin_amdgcn_mfma_f32_16x16x32_bf16(a, b0, a0, 0, 0, 0);
        a1 = __builtin_amdgcn_mfma_f32_16x16x32_bf16(a, b1, a1, 0, 0, 0);
        a2 = __builtin_amdgcn_mfma_f32_16x16x32_bf16(a, b2, a2, 0, 0, 0);
        a3 = __builtin_amdgcn_mfma_f32_16x16x32_bf16(a, b3, a3, 0, 0, 0);
    }
    // C/D layout: col = lane&15, row = (lane>>4)*4 + reg
    int rb = (lane >> 4) * 4, cb = lane & 15;
    #pragma unroll
    for (int q = 0; q < 4; ++q) {
        pout[(rb + q) * 64 +  0 + cb] = a0[q];
        pout[(rb + q) * 64 + 16 + cb] = a1[q];
        pout[(rb + q) * 64 + 32 + cb] = a2[q];
        pout[(rb + q) * 64 + 48 + cb] = a3[q];
    }
}

// ---------------- kernel 3: reduce partials + bias + activations ----------------
__global__ __launch_bounds__(256) void k_act(
    const float* __restrict__ bias,
    const float* __restrict__ Wqb, const float* __restrict__ Wkb, const float* __restrict__ Wvb,
    float* __restrict__ ws) {
    int g = blockIdx.x * 256 + threadIdx.x;   // 0..393215
    if (g < 196608) {
        int r = g >> 6, b = g & 63;
        int t = r >> 4, ro = r & 15;
        const float* P = ws + WS_PG + ro * 64 + b;
        float s = bias[r];
        #pragma unroll
        for (int c = 0; c < 16; ++c) s += P[(size_t)(c * 192 + t) * 1024];
        if (r < 1024)       ws[WS_IGT + r * 64 + b] = expf(s);
        else if (r < 2048)  ws[WS_FGT + (r - 1024) * 64 + b] = expf(s);
        else                ws[WS_OGN + b * HD + (r - 2048)] = 1.f / (1.f + expf(-s));
    } else {
        int e = g - 196608;
        int r2 = e >> 6, b = e & 63;
        int t = r2 >> 4, ro = r2 & 15;
        int sel = r2 >> 10, rr = r2 & 1023;
        const float* P = ws + WS_PQ + ro * 64 + b;
        float s = ((sel == 0) ? Wqb : (sel == 1) ? Wkb : Wvb)[rr];
        #pragma unroll
        for (int c = 0; c < 8; ++c) s += P[(size_t)(c * 192 + t) * 1024];
        if (sel == 0)      ws[WS_QT + rr * 64 + b] = s;
        else if (sel == 1) ws[WS_KN + b * HD + rr] = s;
        else               ws[WS_VT + rr * 64 + b] = s;
    }
}

// ---------------- kernel 4: C update + fused readout partials (round-0 body) ----
__global__ __launch_bounds__(256) void k_update(const float* __restrict__ C,
                                                float* __restrict__ out,
                                                float* __restrict__ ws) {
    int b  = blockIdx.x >> 4;
    int c  = blockIdx.x & 15;
    int i0 = c << 6;
    int tid = threadIdx.x;

    __shared__ float fg_s[64], iv_s[64], q_s[64];
    if (tid < 64) {
        int i = i0 + tid;
        fg_s[tid] = ws[WS_FGT + i * 64 + b];
        iv_s[tid] = ws[WS_IGT + i * 64 + b] * ws[WS_VT + i * 64 + b];
        q_s[tid]  = ws[WS_QT + i * 64 + b];
    }
    __syncthreads();

    v4 k4 = *(const v4*)(ws + WS_KN + b * HD + tid * 4);
    const v4* Cb = (const v4*)(C + (size_t)b * HD * HD) + tid;
    v4*       On = (v4*)(out + NB * HD + (size_t)b * HD * HD) + tid;
    v4 acc = {0.f, 0.f, 0.f, 0.f};

    for (int ii = 0; ii < 64; ++ii) {
        int i = i0 + ii;
        v4 c4 = __builtin_nontemporal_load(&Cb[(size_t)i * 256]);
        float fi = fg_s[ii], ivi = iv_s[ii], qi = q_s[ii];
        v4 cn;
        cn.x = fi * c4.x + ivi * k4.x;
        cn.y = fi * c4.y + ivi * k4.y;
        cn.z = fi * c4.z + ivi * k4.z;
        cn.w = fi * c4.w + ivi * k4.w;
        __builtin_nontemporal_store(cn, &On[(size_t)i * 256]);
        acc.x += qi * cn.x;
        acc.y += qi * cn.y;
        acc.z += qi * cn.z;
        acc.w += qi * cn.w;
    }
    *(v4*)(ws + WS_PART + (size_t)(c * 64 + b) * HD + tid * 4) = acc;
}

// ---------------- kernel 5: finalize h ----------------
__global__ __launch_bounds__(256) void k_final(float* __restrict__ out,
                                               const float* __restrict__ ws) {
    int b = blockIdx.x;
    int tid = threadIdx.x;
    const v4* part = (const v4*)(ws + WS_PART);
    v4 s = {0.f, 0.f, 0.f, 0.f};
    for (int c = 0; c < NCHUNK; ++c) {
        v4 p = part[(size_t)(c * 64 + b) * 256 + tid];
        s.x += p.x; s.y += p.y; s.z += p.z; s.w += p.w;
    }
    v4 o4 = *(const v4*)(ws + WS_OGN + b * HD + tid * 4);
    v4 r;
    r.x = o4.x * s.x; r.y = o4.y * s.y; r.z = o4.z * s.z; r.w = o4.w * s.w;
    *(v4*)(out + b * HD + tid * 4) = r;
}

extern "C" void kernel_launch(void* const* d_in, const int* in_sizes, int n_in,
                              void* d_out, int out_size, void* d_ws, size_t ws_size,
                              hipStream_t stream) {
    const float* input = (const float*)d_in[0];
    const float* h     = (const float*)d_in[1];
    const float* C     = (const float*)d_in[2];
    const float* Wih   = (const float*)d_in[3];
    const float* Whh   = (const float*)d_in[4];
    const float* bias  = (const float*)d_in[5];
    const float* Wq_w  = (const float*)d_in[6];
    const float* Wq_b  = (const float*)d_in[7];
    const float* Wk_w  = (const float*)d_in[8];
    const float* Wk_b  = (const float*)d_in[9];
    const float* Wv_w  = (const float*)d_in[10];
    const float* Wv_b  = (const float*)d_in[11];
    float* out = (float*)d_out;
    float* ws  = (float*)d_ws;

    k_prep<<<4672, 256, 0, stream>>>(input, h, Wih, Whh, Wq_w, Wk_w, Wv_w, ws);
    k_mfma<<<1152, 256, 0, stream>>>(ws);
    k_act<<<1536, 256, 0, stream>>>(bias, Wq_b, Wk_b, Wv_b, ws);
    k_update<<<1024, 256, 0, stream>>>(C, out, ws);
    k_final<<<64, 256, 0, stream>>>(out, ws);
}

// Round 3
// 480.782 us; speedup vs baseline: 1.2682x; 1.0471x over previous
//
#include <hip/hip_runtime.h>
#include <math.h>

typedef float v4 __attribute__((ext_vector_type(4)));
typedef float f32x4 __attribute__((ext_vector_type(4)));
typedef __bf16 bf16x8 __attribute__((ext_vector_type(8)));

#define HD 1024      // hidden dim
#define NB 64        // batch

// ws layout (float offsets)
#define WS_IGT  0         // igT [1024][64]   exp(i-gate), transposed
#define WS_FGT  65536     // fgT [1024][64]   exp(f-gate)
#define WS_QT   131072    // qT  [1024][64]
#define WS_VT   196608    // vT  [1024][64]
#define WS_OGN  262144    // ogN [64][1024]   sigmoid(o), natural
#define WS_KN   327680    // kN  [64][1024]   natural
#define WS_BPK  393216    // bf16 x/h B-fragments [64 ks][4 bt][64 lane][8] = 65536 floats
#define WS_PART 458752    // readout partials [32 c][64 b][1024] = 2,097,152 floats
// total = 2,555,904 floats = 10.2 MB

// ---------------- kernel 1: pack x/h to bf16 MFMA B-fragments (tiny) ------------
// B-fragment (mfma_f32_16x16x32_bf16): lane l holds X[bt*16 + (l&15)][ks*32 + (l>>4)*8 + j]
// ks 0..31 = input, ks 32..63 = h. Layout verified by round-2 pass.
__global__ __launch_bounds__(256) void k_prepb(const float* __restrict__ input,
                                               const float* __restrict__ h,
                                               float* __restrict__ ws) {
    int o = blockIdx.x * 256 + threadIdx.x;     // 0..16383
    int l  = o & 63;
    int bt = (o >> 6) & 3;
    int ks = o >> 8;                            // 0..63
    const float* srcm = (ks < 32) ? input : h;
    const float* src = srcm + (size_t)(bt * 16 + (l & 15)) * HD + (ks & 31) * 32 + (l >> 4) * 8;
    v4 f0 = *(const v4*)src;
    v4 f1 = *(const v4*)(src + 4);
    bf16x8 pk;
    pk[0] = (__bf16)f0.x; pk[1] = (__bf16)f0.y; pk[2] = (__bf16)f0.z; pk[3] = (__bf16)f0.w;
    pk[4] = (__bf16)f1.x; pk[5] = (__bf16)f1.y; pk[6] = (__bf16)f1.z; pk[7] = (__bf16)f1.w;
    *((bf16x8*)((__bf16*)(ws + WS_BPK)) + o) = pk;
}

// ---------------- kernel 2: fused MFMA GEMM + bias + activations ----------------
// One block (4 waves) = one 16-row output tile x 64 batches, full K.
// Waves split K; A (weights) loaded fp32 straight from HBM and converted
// in-register (A-fragment = 32B of one weight row per lane -> fully coalesced,
// weights stream exactly once, no repack). LDS reduction + activation fused.
// blocks 0..191: gates tiles (K=2048: x via Wih then h via Whh)
// blocks 192..383: q/k/v tiles (K=1024)
__global__ __launch_bounds__(256) void k_gemm(
    const float* __restrict__ Wih, const float* __restrict__ Whh, const float* __restrict__ bias,
    const float* __restrict__ Wq, const float* __restrict__ Wqb,
    const float* __restrict__ Wk, const float* __restrict__ Wkb,
    const float* __restrict__ Wv, const float* __restrict__ Wvb,
    float* __restrict__ ws) {
    int tid  = threadIdx.x;
    int lane = tid & 63;
    int w    = tid >> 6;          // 0..3
    int t    = blockIdx.x;

    const bf16x8* Bp = (const bf16x8*)((const __bf16*)(ws + WS_BPK));
    __shared__ f32x4 red[4][4][64];   // [wave][b-tile][lane]

    f32x4 a0 = {0.f, 0.f, 0.f, 0.f};
    f32x4 a1 = a0, a2 = a0, a3 = a0;

    if (t < 192) {
        // gates: rows t*16..t*16+15, wave w owns ksteps w*16..w*16+15
        int row = t * 16 + (lane & 15);
        const float* Wb = (w < 2) ? Wih : Whh;
        const float* wrow = Wb + (size_t)row * HD + (lane >> 4) * 8;
        int cofs = (w < 2) ? 0 : -1024;
        int s0 = w * 16;
        #pragma unroll 4
        for (int s = 0; s < 16; ++s) {
            int ks = s0 + s;
            const float* ap = wrow + ks * 32 + cofs;
            v4 f0 = *(const v4*)ap;
            v4 f1 = *(const v4*)(ap + 4);
            bf16x8 a;
            a[0] = (__bf16)f0.x; a[1] = (__bf16)f0.y; a[2] = (__bf16)f0.z; a[3] = (__bf16)f0.w;
            a[4] = (__bf16)f1.x; a[5] = (__bf16)f1.y; a[6] = (__bf16)f1.z; a[7] = (__bf16)f1.w;
            const bf16x8* bb = Bp + (size_t)ks * 256 + lane;
            bf16x8 b0 = bb[0], b1 = bb[64], b2 = bb[128], b3 = bb[192];
            a0 = __builtin_amdgcn_mfma_f32_16x16x32_bf16(a, b0, a0, 0, 0, 0);
            a1 = __builtin_amdgcn_mfma_f32_16x16x32_bf16(a, b1, a1, 0, 0, 0);
            a2 = __builtin_amdgcn_mfma_f32_16x16x32_bf16(a, b2, a2, 0, 0, 0);
            a3 = __builtin_amdgcn_mfma_f32_16x16x32_bf16(a, b3, a3, 0, 0, 0);
        }
    } else {
        // q/k/v: tile t2, wave w owns ksteps w*8..w*8+7 (all x)
        int t2  = t - 192;
        int sel = t2 >> 6;
        const float* W = (sel == 0) ? Wq : (sel == 1) ? Wk : Wv;
        int row = (t2 & 63) * 16 + (lane & 15);
        const float* wrow = W + (size_t)row * HD + (lane >> 4) * 8;
        int s0 = w * 8;
        #pragma unroll 4
        for (int s = 0; s < 8; ++s) {
            int ks = s0 + s;
            const float* ap = wrow + ks * 32;
            v4 f0 = *(const v4*)ap;
            v4 f1 = *(const v4*)(ap + 4);
            bf16x8 a;
            a[0] = (__bf16)f0.x; a[1] = (__bf16)f0.y; a[2] = (__bf16)f0.z; a[3] = (__bf16)f0.w;
            a[4] = (__bf16)f1.x; a[5] = (__bf16)f1.y; a[6] = (__bf16)f1.z; a[7] = (__bf16)f1.w;
            const bf16x8* bb = Bp + (size_t)ks * 256 + lane;
            bf16x8 b0 = bb[0], b1 = bb[64], b2 = bb[128], b3 = bb[192];
            a0 = __builtin_amdgcn_mfma_f32_16x16x32_bf16(a, b0, a0, 0, 0, 0);
            a1 = __builtin_amdgcn_mfma_f32_16x16x32_bf16(a, b1, a1, 0, 0, 0);
            a2 = __builtin_amdgcn_mfma_f32_16x16x32_bf16(a, b2, a2, 0, 0, 0);
            a3 = __builtin_amdgcn_mfma_f32_16x16x32_bf16(a, b3, a3, 0, 0, 0);
        }
    }

    red[w][0][lane] = a0;
    red[w][1][lane] = a1;
    red[w][2][lane] = a2;
    red[w][3][lane] = a3;
    __syncthreads();

    // reduce 4 waves' K-partials; thread j -> batch b = j&63, rows rgrp*4..rgrp*4+3
    int b    = tid & 63;
    int rgrp = tid >> 6;
    int lane2 = (rgrp << 4) | (b & 15);
    int bt    = b >> 4;
    f32x4 s4 = red[0][bt][lane2];
    s4 += red[1][bt][lane2];
    s4 += red[2][bt][lane2];
    s4 += red[3][bt][lane2];

    if (t < 192) {
        int seg  = t >> 6;                       // 0=i, 1=f, 2=o
        int rloc = (t & 63) * 16 + rgrp * 4;     // row within the 1024-row segment
        int rg   = t * 16 + rgrp * 4;            // global gate row (bias index)
        if (seg == 0) {
            #pragma unroll
            for (int q = 0; q < 4; ++q)
                ws[WS_IGT + (rloc + q) * 64 + b] = expf(s4[q] + bias[rg + q]);
        } else if (seg == 1) {
            #pragma unroll
            for (int q = 0; q < 4; ++q)
                ws[WS_FGT + (rloc + q) * 64 + b] = expf(s4[q] + bias[rg + q]);
        } else {
            v4 o;
            #pragma unroll
            for (int q = 0; q < 4; ++q) {
                float x = s4[q] + bias[rg + q];
                o[q] = 1.f / (1.f + expf(-x));
            }
            *(v4*)(ws + WS_OGN + b * HD + rloc) = o;
        }
    } else {
        int t2   = t - 192;
        int sel  = t2 >> 6;
        int rloc = (t2 & 63) * 16 + rgrp * 4;
        const float* Bv = (sel == 0) ? Wqb : (sel == 1) ? Wkb : Wvb;
        if (sel == 0) {
            #pragma unroll
            for (int q = 0; q < 4; ++q)
                ws[WS_QT + (rloc + q) * 64 + b] = s4[q] + Bv[rloc + q];
        } else if (sel == 1) {
            v4 kv;
            #pragma unroll
            for (int q = 0; q < 4; ++q) kv[q] = s4[q] + Bv[rloc + q];
            *(v4*)(ws + WS_KN + b * HD + rloc) = kv;
        } else {
            #pragma unroll
            for (int q = 0; q < 4; ++q)
                ws[WS_VT + (rloc + q) * 64 + b] = s4[q] + Bv[rloc + q];
        }
    }
}

// ---------------- kernel 3: C update + fused readout partials -------------------
// 2048 blocks (64 b x 32 chunks of 32 rows) -> 8 blocks/CU = 32 waves/CU (occ cap).
// 4-deep batched NT loads for memory-level parallelism.
__global__ __launch_bounds__(256) void k_update(const float* __restrict__ C,
                                                float* __restrict__ out,
                                                float* __restrict__ ws) {
    int b  = blockIdx.x >> 5;
    int c  = blockIdx.x & 31;
    int i0 = c << 5;
    int tid = threadIdx.x;

    __shared__ float fg_s[32], iv_s[32], q_s[32];
    if (tid < 32) {
        int i = i0 + tid;
        fg_s[tid] = ws[WS_FGT + i * 64 + b];
        iv_s[tid] = ws[WS_IGT + i * 64 + b] * ws[WS_VT + i * 64 + b];
        q_s[tid]  = ws[WS_QT + i * 64 + b];
    }
    __syncthreads();

    v4 k4 = *(const v4*)(ws + WS_KN + b * HD + tid * 4);
    const v4* Cb = (const v4*)(C + (size_t)b * HD * HD) + tid;
    v4*       On = (v4*)(out + NB * HD + (size_t)b * HD * HD) + tid;
    v4 acc0 = {0.f, 0.f, 0.f, 0.f};
    v4 acc1 = {0.f, 0.f, 0.f, 0.f};

    #pragma unroll
    for (int ii = 0; ii < 32; ii += 4) {
        size_t r0 = (size_t)(i0 + ii) * 256;
        v4 c0 = __builtin_nontemporal_load(&Cb[r0]);
        v4 c1 = __builtin_nontemporal_load(&Cb[r0 + 256]);
        v4 c2 = __builtin_nontemporal_load(&Cb[r0 + 512]);
        v4 c3 = __builtin_nontemporal_load(&Cb[r0 + 768]);

        float f0 = fg_s[ii + 0], g0 = iv_s[ii + 0], q0 = q_s[ii + 0];
        float f1 = fg_s[ii + 1], g1 = iv_s[ii + 1], q1 = q_s[ii + 1];
        float f2 = fg_s[ii + 2], g2 = iv_s[ii + 2], q2 = q_s[ii + 2];
        float f3 = fg_s[ii + 3], g3 = iv_s[ii + 3], q3 = q_s[ii + 3];

        v4 n0, n1, n2, n3;
        n0.x = f0 * c0.x + g0 * k4.x; n0.y = f0 * c0.y + g0 * k4.y;
        n0.z = f0 * c0.z + g0 * k4.z; n0.w = f0 * c0.w + g0 * k4.w;
        n1.x = f1 * c1.x + g1 * k4.x; n1.y = f1 * c1.y + g1 * k4.y;
        n1.z = f1 * c1.z + g1 * k4.z; n1.w = f1 * c1.w + g1 * k4.w;
        n2.x = f2 * c2.x + g2 * k4.x; n2.y = f2 * c2.y + g2 * k4.y;
        n2.z = f2 * c2.z + g2 * k4.z; n2.w = f2 * c2.w + g2 * k4.w;
        n3.x = f3 * c3.x + g3 * k4.x; n3.y = f3 * c3.y + g3 * k4.y;
        n3.z = f3 * c3.z + g3 * k4.z; n3.w = f3 * c3.w + g3 * k4.w;

        __builtin_nontemporal_store(n0, &On[r0]);
        __builtin_nontemporal_store(n1, &On[r0 + 256]);
        __builtin_nontemporal_store(n2, &On[r0 + 512]);
        __builtin_nontemporal_store(n3, &On[r0 + 768]);

        acc0.x += q0 * n0.x; acc0.y += q0 * n0.y; acc0.z += q0 * n0.z; acc0.w += q0 * n0.w;
        acc1.x += q1 * n1.x; acc1.y += q1 * n1.y; acc1.z += q1 * n1.z; acc1.w += q1 * n1.w;
        acc0.x += q2 * n2.x; acc0.y += q2 * n2.y; acc0.z += q2 * n2.z; acc0.w += q2 * n2.w;
        acc1.x += q3 * n3.x; acc1.y += q3 * n3.y; acc1.z += q3 * n3.z; acc1.w += q3 * n3.w;
    }
    v4 acc;
    acc.x = acc0.x + acc1.x; acc.y = acc0.y + acc1.y;
    acc.z = acc0.z + acc1.z; acc.w = acc0.w + acc1.w;
    *(v4*)(ws + WS_PART + (size_t)(c * 64 + b) * HD + tid * 4) = acc;
}

// ---------------- kernel 4: finalize h ------------------------------------------
__global__ __launch_bounds__(256) void k_final(float* __restrict__ out,
                                               const float* __restrict__ ws) {
    int b = blockIdx.x;
    int tid = threadIdx.x;
    const v4* part = (const v4*)(ws + WS_PART);
    v4 s = {0.f, 0.f, 0.f, 0.f};
    #pragma unroll 4
    for (int c = 0; c < 32; ++c) {
        v4 p = part[(size_t)(c * 64 + b) * 256 + tid];
        s.x += p.x; s.y += p.y; s.z += p.z; s.w += p.w;
    }
    v4 o4 = *(const v4*)(ws + WS_OGN + b * HD + tid * 4);
    v4 r;
    r.x = o4.x * s.x; r.y = o4.y * s.y; r.z = o4.z * s.z; r.w = o4.w * s.w;
    *(v4*)(out + b * HD + tid * 4) = r;
}

extern "C" void kernel_launch(void* const* d_in, const int* in_sizes, int n_in,
                              void* d_out, int out_size, void* d_ws, size_t ws_size,
                              hipStream_t stream) {
    const float* input = (const float*)d_in[0];
    const float* h     = (const float*)d_in[1];
    const float* C     = (const float*)d_in[2];
    const float* Wih   = (const float*)d_in[3];
    const float* Whh   = (const float*)d_in[4];
    const float* bias  = (const float*)d_in[5];
    const float* Wq_w  = (const float*)d_in[6];
    const float* Wq_b  = (const float*)d_in[7];
    const float* Wk_w  = (const float*)d_in[8];
    const float* Wk_b  = (const float*)d_in[9];
    const float* Wv_w  = (const float*)d_in[10];
    const float* Wv_b  = (const float*)d_in[11];
    float* out = (float*)d_out;
    float* ws  = (float*)d_ws;

    k_prepb<<<64, 256, 0, stream>>>(input, h, ws);
    k_gemm<<<384, 256, 0, stream>>>(Wih, Whh, bias, Wq_w, Wq_b, Wk_w, Wk_b, Wv_w, Wv_b, ws);
    k_update<<<2048, 256, 0, stream>>>(C, out, ws);
    k_final<<<64, 256, 0, stream>>>(out, ws);
}